// Round 3
// baseline (3074.968 us; speedup 1.0000x reference)
//
#include <hip/hip_runtime.h>
#include <stdint.h>

// GaitnetActor: B=8192, OPT=16, SHARED=22, UNIQ=8, obs=150 cols.
// Inputs fp32, OUTPUT fp32 (threshold forensics: 2%-of-max fp32 path).
// out[0:131072] = logits (B,16), out[131072:262144] = duration (B,16).
// Fully fused: one block per batch element; shared+unique MLPs recomputed
// per block (~7% extra FLOPs) to avoid any workspace round-trip.

static constexpr int B_   = 8192;
static constexpr int OBS_ = 150;

__global__ __launch_bounds__(256) void k_fused(
    const float* __restrict__ obs,
    const float* __restrict__ sw1, const float* __restrict__ sb1,
    const float* __restrict__ sw2, const float* __restrict__ sb2,
    const float* __restrict__ uw1, const float* __restrict__ ub1,
    const float* __restrict__ uw2, const float* __restrict__ ub2,
    const float* __restrict__ emb,
    const float* __restrict__ tw1, const float* __restrict__ tb1,
    const float* __restrict__ tw2, const float* __restrict__ tb2,
    const float* __restrict__ vw,  const float* __restrict__ vb,
    const float* __restrict__ dw,  const float* __restrict__ db,
    float* __restrict__ out)
{
    __shared__ float o_[152];        // obs row (150 used)
    __shared__ float h1s[256];       // shared-MLP layer1
    __shared__ float h1u[16][128];   // unique-MLP layer1
    __shared__ float tin[16][384];   // trunk input; reused as t2[16][256]
    __shared__ float h1t[16][512];   // trunk layer1
    const int b = blockIdx.x;
    const int t = threadIdx.x;

    if (t < OBS_) o_[t] = obs[b * OBS_ + t];
    __syncthreads();

    // ---- shared MLP layer1: neuron t (22 MACs) ----
    {
        float a = sb1[t];
        #pragma unroll
        for (int k = 0; k < 22; ++k) a += sw1[t * 22 + k] * o_[k];
        h1s[t] = fmaxf(a, 0.f);
    }
    // ---- unique MLP layer1: neuron n=t&127, options o0, o0+2, ... ----
    {
        const int n = t & 127, o0 = t >> 7;
        float w[8];
        #pragma unroll
        for (int k = 0; k < 8; ++k) w[k] = uw1[n * 8 + k];
        const float bias = ub1[n];
        #pragma unroll
        for (int j = 0; j < 8; ++j) {
            const int o = o0 + 2 * j;
            float a = bias;
            #pragma unroll
            for (int k = 0; k < 8; ++k) a += w[k] * o_[22 + o * 8 + k];
            h1u[o][n] = fmaxf(a, 0.f);
        }
    }
    __syncthreads();

    // ---- shared MLP layer2: neuron t; broadcast se into tin cols 0..255 ----
    {
        float a = sb2[t];
        const float* wrow = &sw2[t * 256];
        for (int k = 0; k < 256; k += 4) {
            float4 wv = *reinterpret_cast<const float4*>(&wrow[k]);
            float4 hv = *reinterpret_cast<const float4*>(&h1s[k]);
            a += wv.x * hv.x + wv.y * hv.y + wv.z * hv.z + wv.w * hv.w;
        }
        const float se = fmaxf(a, 0.f);
        #pragma unroll
        for (int r = 0; r < 16; ++r) tin[r][t] = se;
    }
    // ---- unique MLP layer2 + no-op override: into tin cols 256..383 ----
    {
        const int n = t & 127, o0 = t >> 7;
        const float bias = ub2[n];
        const float* wrow = &uw2[n * 128];
        const float e = emb[n];
        float a8[8];
        #pragma unroll
        for (int j = 0; j < 8; ++j) a8[j] = bias;
        for (int k = 0; k < 128; k += 4) {
            float4 wv = *reinterpret_cast<const float4*>(&wrow[k]);
            #pragma unroll
            for (int j = 0; j < 8; ++j) {
                float4 hv = *reinterpret_cast<const float4*>(&h1u[o0 + 2 * j][k]);
                a8[j] += wv.x * hv.x + wv.y * hv.y + wv.z * hv.z + wv.w * hv.w;
            }
        }
        #pragma unroll
        for (int j = 0; j < 8; ++j) {
            const int o = o0 + 2 * j;
            const bool noop = (o_[22 + o * 8] == 1.0f);
            tin[o][256 + n] = noop ? e : fmaxf(a8[j], 0.f);
        }
    }
    __syncthreads();

    // ---- trunk layer1: neurons t and t+256, 16 row-accumulators ----
    #pragma unroll
    for (int half = 0; half < 2; ++half) {
        const int n = t + half * 256;
        float acc[16];
        const float bias = tb1[n];
        #pragma unroll
        for (int r = 0; r < 16; ++r) acc[r] = bias;
        const float* wrow = &tw1[n * 384];
        for (int k = 0; k < 384; k += 4) {
            float4 wv = *reinterpret_cast<const float4*>(&wrow[k]);
            #pragma unroll
            for (int r = 0; r < 16; ++r) {
                float4 xv = *reinterpret_cast<const float4*>(&tin[r][k]);
                acc[r] += wv.x * xv.x + wv.y * xv.y + wv.z * xv.z + wv.w * xv.w;
            }
        }
        #pragma unroll
        for (int r = 0; r < 16; ++r) h1t[r][n] = fmaxf(acc[r], 0.f);
    }
    __syncthreads();

    // ---- trunk layer2: neuron t; write t2 into tin region ----
    {
        float acc[16];
        const float bias = tb2[t];
        #pragma unroll
        for (int r = 0; r < 16; ++r) acc[r] = bias;
        const float* wrow = &tw2[t * 512];
        for (int k = 0; k < 512; k += 4) {
            float4 wv = *reinterpret_cast<const float4*>(&wrow[k]);
            #pragma unroll
            for (int r = 0; r < 16; ++r) {
                float4 xv = *reinterpret_cast<const float4*>(&h1t[r][k]);
                acc[r] += wv.x * xv.x + wv.y * xv.y + wv.z * xv.z + wv.w * xv.w;
            }
        }
        float* t2 = &tin[0][0];
        #pragma unroll
        for (int r = 0; r < 16; ++r) t2[r * 256 + t] = fmaxf(acc[r], 0.f);
    }
    __syncthreads();

    // ---- heads: wave w does rows 4w..4w+3, shuffle-reduce over 64 lanes ----
    {
        const int wave = t >> 6, lane = t & 63;
        const float* t2 = &tin[0][0];
        float vwf[4], dwf[4];
        #pragma unroll
        for (int j = 0; j < 4; ++j) {
            vwf[j] = vw[lane + 64 * j];
            dwf[j] = dw[lane + 64 * j];
        }
        const float vbf = vb[0], dbf = db[0];
        const int g0 = b * 16;
        #pragma unroll
        for (int rr = 0; rr < 4; ++rr) {
            const int r = wave * 4 + rr;
            float sv = 0.f, sd = 0.f;
            #pragma unroll
            for (int j = 0; j < 4; ++j) {
                float tv = t2[r * 256 + lane + 64 * j];
                sv += tv * vwf[j];
                sd += tv * dwf[j];
            }
            #pragma unroll
            for (int off = 32; off > 0; off >>= 1) {
                sv += __shfl_down(sv, off);
                sd += __shfl_down(sd, off);
            }
            if (lane == 0) {
                const int g = g0 + r;
                out[g] = sv + vbf;
                const float z = sd + dbf;
                const float sig = 1.f / (1.f + __expf(-z));
                out[B_ * 16 + g] = sig * 0.4f + 0.1f;
            }
        }
    }
}

extern "C" void kernel_launch(void* const* d_in, const int* in_sizes, int n_in,
                              void* d_out, int out_size, void* d_ws, size_t ws_size,
                              hipStream_t stream) {
    const float* obs = (const float*)d_in[0];
    const float* sw1 = (const float*)d_in[1];
    const float* sb1 = (const float*)d_in[2];
    const float* sw2 = (const float*)d_in[3];
    const float* sb2 = (const float*)d_in[4];
    const float* uw1 = (const float*)d_in[5];
    const float* ub1 = (const float*)d_in[6];
    const float* uw2 = (const float*)d_in[7];
    const float* ub2 = (const float*)d_in[8];
    const float* emb = (const float*)d_in[9];
    const float* tw1 = (const float*)d_in[10];
    const float* tb1 = (const float*)d_in[11];
    const float* tw2 = (const float*)d_in[12];
    const float* tb2 = (const float*)d_in[13];
    const float* vw  = (const float*)d_in[14];
    const float* vb  = (const float*)d_in[15];
    const float* dw  = (const float*)d_in[16];
    const float* db  = (const float*)d_in[17];

    k_fused<<<B_, 256, 0, stream>>>(obs, sw1, sb1, sw2, sb2,
                                    uw1, ub1, uw2, ub2, emb,
                                    tw1, tb1, tw2, tb2,
                                    vw, vb, dw, db, (float*)d_out);
}

// Round 4
// 411.519 us; speedup vs baseline: 7.4722x; 7.4722x over previous
//
#include <hip/hip_runtime.h>
#include <stdint.h>

// GaitnetActor B=8192, OPT=16: MFMA (bf16 in / fp32 acc) for all K>=128 GEMMs.
// Block = 512 thr (8 waves) handles 4 batch elems (M=64 trunk rows). Grid 2048.
// d_ws holds bf16 copies of tw1, tw2, uw2, sw2 (converted by k_conv each call).
// out[0:131072] = logits (B,16) fp32, out[131072:262144] = duration fp32.

static constexpr int B_ = 8192;

typedef __attribute__((ext_vector_type(8))) short bf16x8;
typedef __attribute__((ext_vector_type(4))) float f32x4;

__device__ __forceinline__ float u2f(uint16_t u) {
    union { uint32_t i; float f; } c; c.i = (uint32_t)u << 16; return c.f;
}
__device__ __forceinline__ uint16_t f2u(float f) {
    union { float f; uint32_t i; } c; c.f = f;
    uint32_t x = c.i;
    return (uint16_t)((x + 0x7FFFu + ((x >> 16) & 1u)) >> 16);
}

// ws elem offsets (uint16): tw1 512x384, tw2 256x512, uw2 128x128, sw2 256x256
static constexpr int WTW1 = 0;
static constexpr int WTW2 = 196608;
static constexpr int WUW2 = 327680;
static constexpr int WSW2 = 344064;
static constexpr int WTOT = 409600;

__global__ __launch_bounds__(256) void k_conv(
    const float* __restrict__ tw1, const float* __restrict__ tw2,
    const float* __restrict__ uw2, const float* __restrict__ sw2,
    uint16_t* __restrict__ ws)
{
    int i = blockIdx.x * 256 + threadIdx.x;
    if (i < WTW2)      ws[i] = f2u(tw1[i]);
    else if (i < WUW2) ws[i] = f2u(tw2[i - WTW2]);
    else if (i < WSW2) ws[i] = f2u(uw2[i - WUW2]);
    else if (i < WTOT) ws[i] = f2u(sw2[i - WSW2]);
}

// LDS layout (bytes), all 16B-aligned; padded strides give (stride/4)%32==4
// so 16-lane row-stride access is 2-way bank aliasing (free).
static constexpr int OBS_OFF  = 0;      // float [4][152]  = 2432
static constexpr int NOOP_OFF = 2432;   // float [64]      = 256
static constexpr int SEB_OFF  = 2688;   // bf16  [4][264]  = 2112
static constexpr int REGA_OFF = 4800;   // region A (43264): h1s|h1u|uet, later t2
static constexpr int H1S_OFF  = REGA_OFF;            // bf16 [16][264] = 8448
static constexpr int H1U_OFF  = REGA_OFF + 8448;     // bf16 [64][136] = 17408
static constexpr int UET_OFF  = REGA_OFF + 25856;    // bf16 [64][136] = 17408
static constexpr int T2_OFF   = REGA_OFF;            // bf16 [64][264] = 33792
static constexpr int H1T_OFF  = 48064;  // bf16 [64][520] = 66560
static constexpr int SMEM_SZ  = 114624;

__global__ __launch_bounds__(512, 2) void k_main(
    const float* __restrict__ obs,
    const float* __restrict__ sw1, const float* __restrict__ sb1,
    const float* __restrict__ sb2,
    const float* __restrict__ uw1, const float* __restrict__ ub1,
    const float* __restrict__ ub2, const float* __restrict__ emb,
    const float* __restrict__ tb1, const float* __restrict__ tb2,
    const float* __restrict__ vw,  const float* __restrict__ vb,
    const float* __restrict__ dw,  const float* __restrict__ db,
    const uint16_t* __restrict__ wsb,
    float* __restrict__ out)
{
    __shared__ __align__(16) char smem[SMEM_SZ];
    float*    obsl  = (float*)(smem + OBS_OFF);
    float*    noopf = (float*)(smem + NOOP_OFF);
    uint16_t* seb   = (uint16_t*)(smem + SEB_OFF);
    uint16_t* h1s   = (uint16_t*)(smem + H1S_OFF);
    uint16_t* h1u   = (uint16_t*)(smem + H1U_OFF);
    uint16_t* uet   = (uint16_t*)(smem + UET_OFF);
    uint16_t* t2    = (uint16_t*)(smem + T2_OFF);
    uint16_t* h1t   = (uint16_t*)(smem + H1T_OFF);

    const int t    = threadIdx.x;
    const int wv   = t >> 6;
    const int lane = t & 63;
    const int quad = lane >> 4;
    const int l16  = lane & 15;
    const int b0   = blockIdx.x * 4;

    const uint16_t* tw1b = wsb + WTW1;
    const uint16_t* tw2b = wsb + WTW2;
    const uint16_t* uw2b = wsb + WUW2;
    const uint16_t* sw2b = wsb + WSW2;

    // ---- stage 1: load 4 obs rows ----
    for (int i = t; i < 600; i += 512) {
        int e = i / 150, c = i - e * 150;
        obsl[e * 152 + c] = obs[(size_t)(b0 + e) * 150 + c];
    }
    __syncthreads();

    // ---- stage 2: small layer-1s (VALU) + noop flags ----
    if (t < 64) {
        int e = t >> 4, o = t & 15;
        noopf[t] = (obsl[e * 152 + 22 + o * 8] == 1.0f) ? 1.0f : 0.0f;
    }
    #pragma unroll
    for (int ii = 0; ii < 2; ++ii) {           // shared L1: (e,n) 1024 tasks
        int id = t + ii * 512;
        int e = id >> 8, n = id & 255;
        float a = sb1[n];
        const float* w = &sw1[n * 22];
        const float* x = &obsl[e * 152];
        #pragma unroll
        for (int k = 0; k < 22; ++k) a += w[k] * x[k];
        h1s[e * 264 + n] = f2u(fmaxf(a, 0.f));
    }
    #pragma unroll
    for (int ii = 0; ii < 16; ++ii) {          // unique L1: (row,n) 8192 tasks
        int id = t + ii * 512;
        int row = id >> 7, n = id & 127;
        float a = ub1[n];
        const float* w = &uw1[n * 8];
        const float* x = &obsl[(row >> 4) * 152 + 22 + (row & 15) * 8];
        #pragma unroll
        for (int k = 0; k < 8; ++k) a += w[k] * x[k];
        h1u[row * 136 + n] = f2u(fmaxf(a, 0.f));
    }
    __syncthreads();

    // ---- stage 3a: shared L2 via MFMA (only A-rows 0..3 = elems valid) ----
    {
        #pragma unroll
        for (int nt = 0; nt < 2; ++nt) {
            int n = (wv * 2 + nt) * 16 + l16;
            float bv = sb2[n];
            f32x4 acc = {bv, bv, bv, bv};
            const uint16_t* brow = &sw2b[n * 256 + quad * 8];
            const uint16_t* arow = &h1s[l16 * 264 + quad * 8];
            #pragma unroll
            for (int kk = 0; kk < 8; ++kk) {
                bf16x8 af = *reinterpret_cast<const bf16x8*>(arow + kk * 32);
                bf16x8 bf = *reinterpret_cast<const bf16x8*>(brow + kk * 32);
                acc = __builtin_amdgcn_mfma_f32_16x16x32_bf16(af, bf, acc, 0, 0, 0);
            }
            if (quad == 0) {                    // rows 0..3 = reg idx
                #pragma unroll
                for (int r = 0; r < 4; ++r)
                    seb[r * 264 + n] = f2u(fmaxf(acc[r], 0.f));
            }
        }
    }
    // ---- stage 3b: unique L2 via MFMA + noop override -> uet ----
    {
        int n = wv * 16 + l16;                  // wave owns one 16-col tile
        float bv = ub2[n];
        float ev = emb[n];
        f32x4 acc[4];
        #pragma unroll
        for (int mt = 0; mt < 4; ++mt) acc[mt] = {bv, bv, bv, bv};
        const uint16_t* brow = &uw2b[n * 128 + quad * 8];
        #pragma unroll
        for (int kk = 0; kk < 4; ++kk) {
            bf16x8 bf = *reinterpret_cast<const bf16x8*>(brow + kk * 32);
            #pragma unroll
            for (int mt = 0; mt < 4; ++mt) {
                bf16x8 af = *reinterpret_cast<const bf16x8*>(
                    &h1u[(mt * 16 + l16) * 136 + quad * 8 + kk * 32]);
                acc[mt] = __builtin_amdgcn_mfma_f32_16x16x32_bf16(af, bf, acc[mt], 0, 0, 0);
            }
        }
        #pragma unroll
        for (int mt = 0; mt < 4; ++mt)
            #pragma unroll
            for (int r = 0; r < 4; ++r) {
                int row = mt * 16 + quad * 4 + r;
                float v = (noopf[row] != 0.0f) ? ev : fmaxf(acc[mt][r], 0.f);
                uet[row * 136 + n] = f2u(v);
            }
    }
    __syncthreads();

    // ---- stage 4: trunk L1 (M=64, N=512, K=384) ----
    {
        const int nbase = wv * 64;              // wave owns 64 of 512 neurons
        f32x4 acc[4][4];                        // [mt][nt]
        #pragma unroll
        for (int nt = 0; nt < 4; ++nt) {
            float bv = tb1[nbase + nt * 16 + l16];
            #pragma unroll
            for (int mt = 0; mt < 4; ++mt) acc[mt][nt] = {bv, bv, bv, bv};
        }
        // k in [0,256): A = seb[e] broadcast (address has no l16 term)
        #pragma unroll
        for (int kk = 0; kk < 8; ++kk) {
            int koff = kk * 32 + quad * 8;
            bf16x8 bfr[4];
            #pragma unroll
            for (int nt = 0; nt < 4; ++nt)
                bfr[nt] = *reinterpret_cast<const bf16x8*>(
                    &tw1b[(nbase + nt * 16 + l16) * 384 + koff]);
            #pragma unroll
            for (int mt = 0; mt < 4; ++mt) {
                bf16x8 af = *reinterpret_cast<const bf16x8*>(&seb[mt * 264 + koff]);
                #pragma unroll
                for (int nt = 0; nt < 4; ++nt)
                    acc[mt][nt] = __builtin_amdgcn_mfma_f32_16x16x32_bf16(
                        af, bfr[nt], acc[mt][nt], 0, 0, 0);
            }
        }
        // k in [256,384): A = uet rows
        #pragma unroll
        for (int kk = 0; kk < 4; ++kk) {
            int koff = kk * 32 + quad * 8;
            bf16x8 bfr[4];
            #pragma unroll
            for (int nt = 0; nt < 4; ++nt)
                bfr[nt] = *reinterpret_cast<const bf16x8*>(
                    &tw1b[(nbase + nt * 16 + l16) * 384 + 256 + koff]);
            #pragma unroll
            for (int mt = 0; mt < 4; ++mt) {
                bf16x8 af = *reinterpret_cast<const bf16x8*>(
                    &uet[(mt * 16 + l16) * 136 + koff]);
                #pragma unroll
                for (int nt = 0; nt < 4; ++nt)
                    acc[mt][nt] = __builtin_amdgcn_mfma_f32_16x16x32_bf16(
                        af, bfr[nt], acc[mt][nt], 0, 0, 0);
            }
        }
        #pragma unroll
        for (int mt = 0; mt < 4; ++mt)
            #pragma unroll
            for (int nt = 0; nt < 4; ++nt)
                #pragma unroll
                for (int r = 0; r < 4; ++r) {
                    int row = mt * 16 + quad * 4 + r;
                    int n = nbase + nt * 16 + l16;
                    h1t[row * 520 + n] = f2u(fmaxf(acc[mt][nt][r], 0.f));
                }
    }
    __syncthreads();

    // ---- stage 5: trunk L2 (M=64, N=256, K=512) -> t2 ----
    {
        f32x4 acc[4][2];
        #pragma unroll
        for (int nt = 0; nt < 2; ++nt) {
            float bv = tb2[(wv * 2 + nt) * 16 + l16];
            #pragma unroll
            for (int mt = 0; mt < 4; ++mt) acc[mt][nt] = {bv, bv, bv, bv};
        }
        #pragma unroll
        for (int kk = 0; kk < 16; ++kk) {
            int koff = kk * 32 + quad * 8;
            bf16x8 bfr[2];
            #pragma unroll
            for (int nt = 0; nt < 2; ++nt)
                bfr[nt] = *reinterpret_cast<const bf16x8*>(
                    &tw2b[((wv * 2 + nt) * 16 + l16) * 512 + koff]);
            #pragma unroll
            for (int mt = 0; mt < 4; ++mt) {
                bf16x8 af = *reinterpret_cast<const bf16x8*>(
                    &h1t[(mt * 16 + l16) * 520 + koff]);
                #pragma unroll
                for (int nt = 0; nt < 2; ++nt)
                    acc[mt][nt] = __builtin_amdgcn_mfma_f32_16x16x32_bf16(
                        af, bfr[nt], acc[mt][nt], 0, 0, 0);
            }
        }
        #pragma unroll
        for (int mt = 0; mt < 4; ++mt)
            #pragma unroll
            for (int nt = 0; nt < 2; ++nt)
                #pragma unroll
                for (int r = 0; r < 4; ++r) {
                    int row = mt * 16 + quad * 4 + r;
                    int n = (wv * 2 + nt) * 16 + l16;
                    t2[row * 264 + n] = f2u(fmaxf(acc[mt][nt][r], 0.f));
                }
    }
    __syncthreads();

    // ---- stage 6: heads, wave wv does rows 8wv..8wv+7 ----
    {
        float vwf[4], dwf[4];
        #pragma unroll
        for (int j = 0; j < 4; ++j) {
            vwf[j] = vw[lane + 64 * j];
            dwf[j] = dw[lane + 64 * j];
        }
        const float vbf = vb[0], dbf = db[0];
        #pragma unroll
        for (int rr = 0; rr < 8; ++rr) {
            int row = wv * 8 + rr;
            float sv = 0.f, sd = 0.f;
            #pragma unroll
            for (int j = 0; j < 4; ++j) {
                float tv = u2f(t2[row * 264 + lane + 64 * j]);
                sv += tv * vwf[j];
                sd += tv * dwf[j];
            }
            #pragma unroll
            for (int off = 32; off > 0; off >>= 1) {
                sv += __shfl_down(sv, off);
                sd += __shfl_down(sd, off);
            }
            if (lane == 0) {
                int g = blockIdx.x * 64 + row;
                out[g] = sv + vbf;
                float z = sd + dbf;
                float sig = 1.f / (1.f + __expf(-z));
                out[B_ * 16 + g] = sig * 0.4f + 0.1f;
            }
        }
    }
}

extern "C" void kernel_launch(void* const* d_in, const int* in_sizes, int n_in,
                              void* d_out, int out_size, void* d_ws, size_t ws_size,
                              hipStream_t stream) {
    const float* obs = (const float*)d_in[0];
    const float* sw1 = (const float*)d_in[1];
    const float* sb1 = (const float*)d_in[2];
    const float* sw2 = (const float*)d_in[3];
    const float* sb2 = (const float*)d_in[4];
    const float* uw1 = (const float*)d_in[5];
    const float* ub1 = (const float*)d_in[6];
    const float* uw2 = (const float*)d_in[7];
    const float* ub2 = (const float*)d_in[8];
    const float* emb = (const float*)d_in[9];
    const float* tw1 = (const float*)d_in[10];
    const float* tb1 = (const float*)d_in[11];
    const float* tw2 = (const float*)d_in[12];
    const float* tb2 = (const float*)d_in[13];
    const float* vw  = (const float*)d_in[14];
    const float* vb  = (const float*)d_in[15];
    const float* dw  = (const float*)d_in[16];
    const float* db  = (const float*)d_in[17];

    uint16_t* wsb = (uint16_t*)d_ws;

    k_conv<<<(WTOT + 255) / 256, 256, 0, stream>>>(tw1, tw2, uw2, sw2, wsb);
    k_main<<<B_ / 4, 512, 0, stream>>>(obs, sw1, sb1, sb2, uw1, ub1, ub2, emb,
                                       tb1, tb2, vw, vb, dw, db, wsb,
                                       (float*)d_out);
}

// Round 5
// 316.086 us; speedup vs baseline: 9.7283x; 1.3019x over previous
//
#include <hip/hip_runtime.h>
#include <stdint.h>

// GaitnetActor B=8192, OPT=16. Round 5: M=128 rows/block (8 batch elems),
// K-chunked trunk L1->L2 fusion (h1t chunk of 128 neurons in LDS), depth-2
// software prefetch of weight B-fragments. bf16 MFMA / fp32 accum.
// out[0:131072] = logits fp32, out[131072:262144] = duration fp32.

static constexpr int B_ = 8192;

typedef __attribute__((ext_vector_type(8))) short bf16x8;
typedef __attribute__((ext_vector_type(4))) float f32x4;

__device__ __forceinline__ float u2f(uint16_t u) {
    union { uint32_t i; float f; } c; c.i = (uint32_t)u << 16; return c.f;
}
__device__ __forceinline__ uint16_t f2u(float f) {
    union { float f; uint32_t i; } c; c.f = f;
    uint32_t x = c.i;
    return (uint16_t)((x + 0x7FFFu + ((x >> 16) & 1u)) >> 16);
}

// ws elem offsets (uint16): tw1 512x384, tw2 256x512, uw2 128x128, sw2 256x256
static constexpr int WTW1 = 0;
static constexpr int WTW2 = 196608;
static constexpr int WUW2 = 327680;
static constexpr int WSW2 = 344064;
static constexpr int WTOT = 409600;

__global__ __launch_bounds__(256) void k_conv(
    const float* __restrict__ tw1, const float* __restrict__ tw2,
    const float* __restrict__ uw2, const float* __restrict__ sw2,
    uint16_t* __restrict__ ws)
{
    int i = blockIdx.x * 256 + threadIdx.x;
    if (i < WTW2)      ws[i] = f2u(tw1[i]);
    else if (i < WUW2) ws[i] = f2u(tw2[i - WTW2]);
    else if (i < WSW2) ws[i] = f2u(uw2[i - WUW2]);
    else if (i < WTOT) ws[i] = f2u(sw2[i - WSW2]);
}

// LDS layout (bytes). Strides 136/264 elems -> dword stride %32 == 4 (2-way
// bank aliasing, free per m136). All offsets 16B-aligned.
static constexpr int OBS_OFF  = 0;       // float [8][152]  = 4864
static constexpr int NOOP_OFF = 4864;    // float [128]     = 512
static constexpr int SEB_OFF  = 5376;    // bf16  [8][264]  = 4224
static constexpr int UET_OFF  = 9600;    // bf16  [128][136]= 34816
static constexpr int H1U_OFF  = 44416;   // bf16  [128][136]= 34816
static constexpr int H1T_OFF  = 79232;   // bf16  [128][136]= 34816 (chunk)
static constexpr int H1S_OFF  = H1T_OFF; // bf16  [8][264]  (dead before h1t)
static constexpr int T2_OFF   = H1U_OFF; // bf16  [128][264]= 67584 (overlay)
static constexpr int SMEM_SZ  = 114048;

__global__ __launch_bounds__(512, 2) void k_main(
    const float* __restrict__ obs,
    const float* __restrict__ sw1, const float* __restrict__ sb1,
    const float* __restrict__ sb2,
    const float* __restrict__ uw1, const float* __restrict__ ub1,
    const float* __restrict__ ub2, const float* __restrict__ emb,
    const float* __restrict__ tb1, const float* __restrict__ tb2,
    const float* __restrict__ vw,  const float* __restrict__ vb,
    const float* __restrict__ dw,  const float* __restrict__ db,
    const uint16_t* __restrict__ wsb,
    float* __restrict__ out)
{
    __shared__ __align__(16) char smem[SMEM_SZ];
    float*    obsl  = (float*)(smem + OBS_OFF);
    float*    noopf = (float*)(smem + NOOP_OFF);
    uint16_t* seb   = (uint16_t*)(smem + SEB_OFF);
    uint16_t* uet   = (uint16_t*)(smem + UET_OFF);
    uint16_t* h1u   = (uint16_t*)(smem + H1U_OFF);
    uint16_t* h1t   = (uint16_t*)(smem + H1T_OFF);
    uint16_t* h1s   = (uint16_t*)(smem + H1S_OFF);
    uint16_t* t2    = (uint16_t*)(smem + T2_OFF);

    const int t    = threadIdx.x;
    const int wv   = t >> 6;
    const int lane = t & 63;
    const int quad = lane >> 4;
    const int l16  = lane & 15;
    const int b0   = blockIdx.x * 8;

    const uint16_t* tw1b = wsb + WTW1;
    const uint16_t* tw2b = wsb + WTW2;
    const uint16_t* uw2b = wsb + WUW2;
    const uint16_t* sw2b = wsb + WSW2;

    // ---- stage 1: load 8 obs rows ----
    for (int i = t; i < 1200; i += 512) {
        int e = i / 150, c = i - e * 150;
        obsl[e * 152 + c] = obs[(size_t)(b0 + e) * 150 + c];
    }
    __syncthreads();

    // ---- stage 2: small layer-1s (VALU) + noop flags ----
    if (t < 128) {
        int e = t >> 4, o = t & 15;
        noopf[t] = (obsl[e * 152 + 22 + o * 8] == 1.0f) ? 1.0f : 0.0f;
    }
    {   // shared L1: 8 elems x 256 neurons; n fixed per thread
        const int n = t & 255;
        float w[22];
        #pragma unroll
        for (int k = 0; k < 22; ++k) w[k] = sw1[n * 22 + k];
        const float bias = sb1[n];
        #pragma unroll
        for (int ii = 0; ii < 4; ++ii) {
            int e = (t >> 8) + 2 * ii;
            float a = bias;
            const float* x = &obsl[e * 152];
            #pragma unroll
            for (int k = 0; k < 22; ++k) a += w[k] * x[k];
            h1s[e * 264 + n] = f2u(fmaxf(a, 0.f));
        }
    }
    {   // unique L1: 128 rows x 128 neurons; n fixed per thread
        const int n = t & 127;
        float w[8];
        #pragma unroll
        for (int k = 0; k < 8; ++k) w[k] = uw1[n * 8 + k];
        const float bias = ub1[n];
        #pragma unroll
        for (int ii = 0; ii < 32; ++ii) {
            int row = (t >> 7) + 4 * ii;
            const float* x = &obsl[(row >> 4) * 152 + 22 + (row & 15) * 8];
            float a = bias;
            #pragma unroll
            for (int k = 0; k < 8; ++k) a += w[k] * x[k];
            h1u[row * 136 + n] = f2u(fmaxf(a, 0.f));
        }
    }
    __syncthreads();

    // ---- stage 3a: shared L2 via MFMA -> seb[8][264] ----
    {
        #pragma unroll
        for (int nt = 0; nt < 2; ++nt) {
            int n = (wv * 2 + nt) * 16 + l16;
            float bv = sb2[n];
            f32x4 acc = {bv, bv, bv, bv};
            const uint16_t* brow = &sw2b[n * 256 + quad * 8];
            const uint16_t* arow = &h1s[l16 * 264 + quad * 8];
            #pragma unroll
            for (int kk = 0; kk < 8; ++kk) {
                bf16x8 af = *reinterpret_cast<const bf16x8*>(arow + kk * 32);
                bf16x8 bf = *reinterpret_cast<const bf16x8*>(brow + kk * 32);
                acc = __builtin_amdgcn_mfma_f32_16x16x32_bf16(af, bf, acc, 0, 0, 0);
            }
            if (quad < 2) {                     // rows 0..7 valid (8 elems)
                #pragma unroll
                for (int r = 0; r < 4; ++r)
                    seb[(quad * 4 + r) * 264 + n] = f2u(fmaxf(acc[r], 0.f));
            }
        }
    }
    // ---- stage 3b: unique L2 via MFMA + noop override -> uet[128][136] ----
    {
        int n = wv * 16 + l16;
        float bv = ub2[n];
        float ev = emb[n];
        f32x4 acc[8];
        #pragma unroll
        for (int mt = 0; mt < 8; ++mt) acc[mt] = {bv, bv, bv, bv};
        const uint16_t* brow = &uw2b[n * 128 + quad * 8];
        #pragma unroll
        for (int kk = 0; kk < 4; ++kk) {
            bf16x8 bf = *reinterpret_cast<const bf16x8*>(brow + kk * 32);
            #pragma unroll
            for (int mt = 0; mt < 8; ++mt) {
                bf16x8 af = *reinterpret_cast<const bf16x8*>(
                    &h1u[(mt * 16 + l16) * 136 + quad * 8 + kk * 32]);
                acc[mt] = __builtin_amdgcn_mfma_f32_16x16x32_bf16(af, bf, acc[mt], 0, 0, 0);
            }
        }
        #pragma unroll
        for (int mt = 0; mt < 8; ++mt)
            #pragma unroll
            for (int r = 0; r < 4; ++r) {
                int row = mt * 16 + quad * 4 + r;
                float v = (noopf[row] != 0.0f) ? ev : fmaxf(acc[mt][r], 0.f);
                uet[row * 136 + n] = f2u(v);
            }
    }

    // ---- stages 4/5 fused: trunk L1 in 4 chunks of 128 neurons, each
    //      immediately accumulated into persistent trunk-L2 registers ----
    const int mhalf = wv >> 2;                  // M-half: 64 rows
    const int nq    = wv & 3;                   // N-quarter

    f32x4 acc2[4][4];                           // trunk L2: M=64 x N=64 / wave
    #pragma unroll
    for (int nt = 0; nt < 4; ++nt) {
        float bv = tb2[nq * 64 + nt * 16 + l16];
        #pragma unroll
        for (int mt = 0; mt < 4; ++mt) acc2[mt][nt] = {bv, bv, bv, bv};
    }

    for (int nc = 0; nc < 4; ++nc) {
        __syncthreads();                        // uet/seb ready (nc=0) / h1t reuse
        // ---- L1 chunk: M=128 x N=128, K=384; wave = M=64 x N=32 ----
        {
            f32x4 acc1[4][2];
            #pragma unroll
            for (int nt = 0; nt < 2; ++nt) {
                float bv = tb1[nc * 128 + nq * 32 + nt * 16 + l16];
                #pragma unroll
                for (int mt = 0; mt < 4; ++mt) acc1[mt][nt] = {bv, bv, bv, bv};
            }
            const uint16_t* bb = tw1b + (nc * 128 + nq * 32 + l16) * 384 + quad * 8;
            bf16x8 bA[2], bB[2];
            #pragma unroll
            for (int nt = 0; nt < 2; ++nt) {
                bA[nt] = *reinterpret_cast<const bf16x8*>(bb + nt * 6144);
                bB[nt] = *reinterpret_cast<const bf16x8*>(bb + nt * 6144 + 32);
            }
            #pragma unroll
            for (int kk = 0; kk < 12; ++kk) {
                bf16x8 bN[2];
                if (kk < 10) {
                    #pragma unroll
                    for (int nt = 0; nt < 2; ++nt)
                        bN[nt] = *reinterpret_cast<const bf16x8*>(
                            bb + nt * 6144 + (kk + 2) * 32);
                }
                bf16x8 af[4];
                if (kk < 8) {
                    #pragma unroll
                    for (int mt = 0; mt < 4; ++mt)
                        af[mt] = *reinterpret_cast<const bf16x8*>(
                            &seb[(mhalf * 4 + mt) * 264 + kk * 32 + quad * 8]);
                } else {
                    #pragma unroll
                    for (int mt = 0; mt < 4; ++mt)
                        af[mt] = *reinterpret_cast<const bf16x8*>(
                            &uet[(mhalf * 64 + mt * 16 + l16) * 136 +
                                 (kk - 8) * 32 + quad * 8]);
                }
                #pragma unroll
                for (int mt = 0; mt < 4; ++mt)
                    #pragma unroll
                    for (int nt = 0; nt < 2; ++nt)
                        acc1[mt][nt] = __builtin_amdgcn_mfma_f32_16x16x32_bf16(
                            af[mt], bA[nt], acc1[mt][nt], 0, 0, 0);
                #pragma unroll
                for (int nt = 0; nt < 2; ++nt) { bA[nt] = bB[nt]; bB[nt] = bN[nt]; }
            }
            #pragma unroll
            for (int mt = 0; mt < 4; ++mt)
                #pragma unroll
                for (int nt = 0; nt < 2; ++nt)
                    #pragma unroll
                    for (int r = 0; r < 4; ++r) {
                        int row = mhalf * 64 + mt * 16 + quad * 4 + r;
                        int col = nq * 32 + nt * 16 + l16;
                        h1t[row * 136 + col] = f2u(fmaxf(acc1[mt][nt][r], 0.f));
                    }
        }
        __syncthreads();
        // ---- L2 accumulate: K-chunk of 128; wave = M=64 x N=64 ----
        {
            const uint16_t* cb = tw2b + (nq * 64 + l16) * 512 + nc * 128 + quad * 8;
            bf16x8 cA[4], cB[4];
            #pragma unroll
            for (int nt = 0; nt < 4; ++nt) {
                cA[nt] = *reinterpret_cast<const bf16x8*>(cb + nt * 8192);
                cB[nt] = *reinterpret_cast<const bf16x8*>(cb + nt * 8192 + 32);
            }
            #pragma unroll
            for (int k2 = 0; k2 < 4; ++k2) {
                bf16x8 cN[4];
                if (k2 < 2) {
                    #pragma unroll
                    for (int nt = 0; nt < 4; ++nt)
                        cN[nt] = *reinterpret_cast<const bf16x8*>(
                            cb + nt * 8192 + (k2 + 2) * 32);
                }
                bf16x8 af[4];
                #pragma unroll
                for (int mt = 0; mt < 4; ++mt)
                    af[mt] = *reinterpret_cast<const bf16x8*>(
                        &h1t[(mhalf * 64 + mt * 16 + l16) * 136 +
                             k2 * 32 + quad * 8]);
                #pragma unroll
                for (int mt = 0; mt < 4; ++mt)
                    #pragma unroll
                    for (int nt = 0; nt < 4; ++nt)
                        acc2[mt][nt] = __builtin_amdgcn_mfma_f32_16x16x32_bf16(
                            af[mt], cA[nt], acc2[mt][nt], 0, 0, 0);
                #pragma unroll
                for (int nt = 0; nt < 4; ++nt) { cA[nt] = cB[nt]; cB[nt] = cN[nt]; }
            }
        }
    }
    __syncthreads();                            // last h1t read done
    // ---- t2 epilogue (overlays h1u+h1t) ----
    #pragma unroll
    for (int mt = 0; mt < 4; ++mt)
        #pragma unroll
        for (int nt = 0; nt < 4; ++nt)
            #pragma unroll
            for (int r = 0; r < 4; ++r) {
                int row = mhalf * 64 + mt * 16 + quad * 4 + r;
                int col = nq * 64 + nt * 16 + l16;
                t2[row * 264 + col] = f2u(fmaxf(acc2[mt][nt][r], 0.f));
            }
    __syncthreads();

    // ---- heads: wave wv does rows 16wv..16wv+15 ----
    {
        float vwf[4], dwf[4];
        #pragma unroll
        for (int j = 0; j < 4; ++j) {
            vwf[j] = vw[lane + 64 * j];
            dwf[j] = dw[lane + 64 * j];
        }
        const float vbf = vb[0], dbf = db[0];
        #pragma unroll
        for (int rr = 0; rr < 16; ++rr) {
            int row = wv * 16 + rr;
            float sv = 0.f, sd = 0.f;
            #pragma unroll
            for (int j = 0; j < 4; ++j) {
                float tv = u2f(t2[row * 264 + lane + 64 * j]);
                sv += tv * vwf[j];
                sd += tv * dwf[j];
            }
            #pragma unroll
            for (int off = 32; off > 0; off >>= 1) {
                sv += __shfl_down(sv, off);
                sd += __shfl_down(sd, off);
            }
            if (lane == 0) {
                int g = blockIdx.x * 128 + row;
                out[g] = sv + vbf;
                float z = sd + dbf;
                float sig = 1.f / (1.f + __expf(-z));
                out[B_ * 16 + g] = sig * 0.4f + 0.1f;
            }
        }
    }
}

extern "C" void kernel_launch(void* const* d_in, const int* in_sizes, int n_in,
                              void* d_out, int out_size, void* d_ws, size_t ws_size,
                              hipStream_t stream) {
    const float* obs = (const float*)d_in[0];
    const float* sw1 = (const float*)d_in[1];
    const float* sb1 = (const float*)d_in[2];
    const float* sw2 = (const float*)d_in[3];
    const float* sb2 = (const float*)d_in[4];
    const float* uw1 = (const float*)d_in[5];
    const float* ub1 = (const float*)d_in[6];
    const float* uw2 = (const float*)d_in[7];
    const float* ub2 = (const float*)d_in[8];
    const float* emb = (const float*)d_in[9];
    const float* tw1 = (const float*)d_in[10];
    const float* tb1 = (const float*)d_in[11];
    const float* tw2 = (const float*)d_in[12];
    const float* tb2 = (const float*)d_in[13];
    const float* vw  = (const float*)d_in[14];
    const float* vb  = (const float*)d_in[15];
    const float* dw  = (const float*)d_in[16];
    const float* db  = (const float*)d_in[17];

    uint16_t* wsb = (uint16_t*)d_ws;

    k_conv<<<(WTOT + 255) / 256, 256, 0, stream>>>(tw1, tw2, uw2, sw2, wsb);
    k_main<<<B_ / 8, 512, 0, stream>>>(obs, sw1, sb1, sb2, uw1, ub1, ub2, emb,
                                       tb1, tb2, vw, vb, dw, db, wsb,
                                       (float*)d_out);
}

// Round 6
// 294.830 us; speedup vs baseline: 10.4296x; 1.0721x over previous
//
#include <hip/hip_runtime.h>
#include <stdint.h>

// GaitnetActor B=8192, OPT=16. Round 6: M=64 rows/block (4 batch elems),
// grid 2048, LDS ~75 KB -> 2 blocks/CU (16 waves/CU) so barriers overlap.
// Double-buffered h1t chunk (1 barrier per N-chunk). Vectorized stage-2 LDS
// reads (obs stored with uniq cols shifted +2 for float4 alignment).
// bf16 MFMA / fp32 accum. out[0:131072]=logits fp32, [131072:262144]=duration.

static constexpr int B_ = 8192;

typedef __attribute__((ext_vector_type(8))) short bf16x8;
typedef __attribute__((ext_vector_type(4))) float f32x4;

__device__ __forceinline__ float u2f(uint16_t u) {
    union { uint32_t i; float f; } c; c.i = (uint32_t)u << 16; return c.f;
}
__device__ __forceinline__ uint16_t f2u(float f) {
    union { float f; uint32_t i; } c; c.f = f;
    uint32_t x = c.i;
    return (uint16_t)((x + 0x7FFFu + ((x >> 16) & 1u)) >> 16);
}

// ws elem offsets (uint16): tw1 512x384, tw2 256x512, uw2 128x128, sw2 256x256
static constexpr int WTW1 = 0;
static constexpr int WTW2 = 196608;
static constexpr int WUW2 = 327680;
static constexpr int WSW2 = 344064;
static constexpr int WTOT = 409600;

__global__ __launch_bounds__(256) void k_conv(
    const float* __restrict__ tw1, const float* __restrict__ tw2,
    const float* __restrict__ uw2, const float* __restrict__ sw2,
    uint16_t* __restrict__ ws)
{
    int i4 = blockIdx.x * 256 + threadIdx.x;   // one float4 per thread
    int i = i4 * 4;
    const float* src;
    if (i < WTW2)      src = tw1 + i;
    else if (i < WUW2) src = tw2 + (i - WTW2);
    else if (i < WSW2) src = uw2 + (i - WUW2);
    else               src = sw2 + (i - WSW2);
    float4 v = *reinterpret_cast<const float4*>(src);
    ushort4 o;
    o.x = f2u(v.x); o.y = f2u(v.y); o.z = f2u(v.z); o.w = f2u(v.w);
    *reinterpret_cast<ushort4*>(ws + i) = o;
}

// LDS layout (bytes). Elem strides 136/264 -> dword stride %32 == 4 (2-way
// bank aliasing, free per m136). All offsets 16B-aligned.
static constexpr int OBS_OFF  = 0;       // float [4][152] = 2432 (uniq @ +24)
static constexpr int NOOP_OFF = 2432;    // float [64]     = 256
static constexpr int SEB_OFF  = 2688;    // bf16  [4][264] = 2112
static constexpr int H1S_OFF  = 4800;    // bf16  [4][264] = 2112
static constexpr int H1U_OFF  = 6912;    // bf16  [64][136]= 17408
static constexpr int UET_OFF  = 24320;   // bf16  [64][136]= 17408
static constexpr int H1TA_OFF = 41728;   // bf16  [64][136]= 17408
static constexpr int H1TB_OFF = 59136;   // bf16  [64][136]= 17408
static constexpr int T2_OFF   = H1U_OFF; // bf16  [64][264]= 33792 (overlay)
static constexpr int SMEM_SZ  = 76544;   // 74.75 KB -> 2 blocks/CU

__global__ __launch_bounds__(512, 4) void k_main(
    const float* __restrict__ obs,
    const float* __restrict__ sw1, const float* __restrict__ sb1,
    const float* __restrict__ sb2,
    const float* __restrict__ uw1, const float* __restrict__ ub1,
    const float* __restrict__ ub2, const float* __restrict__ emb,
    const float* __restrict__ tb1, const float* __restrict__ tb2,
    const float* __restrict__ vw,  const float* __restrict__ vb,
    const float* __restrict__ dw,  const float* __restrict__ db,
    const uint16_t* __restrict__ wsb,
    float* __restrict__ out)
{
    __shared__ __align__(16) char smem[SMEM_SZ];
    float*    obsl  = (float*)(smem + OBS_OFF);
    float*    noopf = (float*)(smem + NOOP_OFF);
    uint16_t* seb   = (uint16_t*)(smem + SEB_OFF);
    uint16_t* h1s   = (uint16_t*)(smem + H1S_OFF);
    uint16_t* h1u   = (uint16_t*)(smem + H1U_OFF);
    uint16_t* uet   = (uint16_t*)(smem + UET_OFF);
    uint16_t* h1ta  = (uint16_t*)(smem + H1TA_OFF);
    uint16_t* h1tb  = (uint16_t*)(smem + H1TB_OFF);
    uint16_t* t2    = (uint16_t*)(smem + T2_OFF);

    const int t    = threadIdx.x;
    const int wv   = t >> 6;
    const int lane = t & 63;
    const int quad = lane >> 4;
    const int l16  = lane & 15;
    const int b0   = blockIdx.x * 4;

    const uint16_t* tw1b = wsb + WTW1;
    const uint16_t* tw2b = wsb + WTW2;
    const uint16_t* uw2b = wsb + WUW2;
    const uint16_t* sw2b = wsb + WSW2;

    // ---- stage 1: load 4 obs rows, uniq cols shifted +2 for alignment ----
    for (int i = t; i < 600; i += 512) {
        int e = i / 150, c = i - e * 150;
        int dst = (c < 22) ? c : c + 2;
        obsl[e * 152 + dst] = obs[(size_t)(b0 + e) * 150 + c];
    }
    __syncthreads();

    // ---- stage 2: small layer-1s (VALU, vectorized LDS reads) ----
    if (t < 64) {
        int e = t >> 4, o = t & 15;
        noopf[t] = (obsl[e * 152 + 24 + o * 8] == 1.0f) ? 1.0f : 0.0f;
    }
    {   // shared L1: 4 elems x 256 neurons; n fixed per thread (2 iters)
        const int n = t & 255;
        float w[22];
        #pragma unroll
        for (int k = 0; k < 22; ++k) w[k] = sw1[n * 22 + k];
        const float bias = sb1[n];
        #pragma unroll
        for (int ii = 0; ii < 2; ++ii) {
            int e = (t >> 8) + 2 * ii;
            const float2* xp = (const float2*)&obsl[e * 152];
            float a = bias;
            #pragma unroll
            for (int k = 0; k < 11; ++k) {
                float2 x2 = xp[k];
                a += w[2 * k] * x2.x + w[2 * k + 1] * x2.y;
            }
            h1s[e * 264 + n] = f2u(fmaxf(a, 0.f));
        }
    }
    {   // unique L1: 64 rows x 128 neurons; n fixed per thread (16 iters)
        const int n = t & 127;
        float w[8];
        #pragma unroll
        for (int k = 0; k < 8; ++k) w[k] = uw1[n * 8 + k];
        const float bias = ub1[n];
        #pragma unroll
        for (int ii = 0; ii < 16; ++ii) {
            int row = (t >> 7) + 4 * ii;
            const float4* xp = (const float4*)&obsl[(row >> 4) * 152 + 24 + (row & 15) * 8];
            float4 xa = xp[0], xb = xp[1];
            float a = bias + w[0] * xa.x + w[1] * xa.y + w[2] * xa.z + w[3] * xa.w
                           + w[4] * xb.x + w[5] * xb.y + w[6] * xb.z + w[7] * xb.w;
            h1u[row * 136 + n] = f2u(fmaxf(a, 0.f));
        }
    }
    __syncthreads();

    // ---- stage 3a: shared L2 via MFMA -> seb[4][264] ----
    {
        #pragma unroll
        for (int nt = 0; nt < 2; ++nt) {
            int n = (wv * 2 + nt) * 16 + l16;
            float bv = sb2[n];
            f32x4 acc = {bv, bv, bv, bv};
            const uint16_t* brow = &sw2b[n * 256 + quad * 8];
            const uint16_t* arow = &h1s[l16 * 264 + quad * 8];  // rows>=4 read
            #pragma unroll                                       // finite junk
            for (int kk = 0; kk < 8; ++kk) {
                bf16x8 af = *reinterpret_cast<const bf16x8*>(arow + kk * 32);
                bf16x8 bf = *reinterpret_cast<const bf16x8*>(brow + kk * 32);
                acc = __builtin_amdgcn_mfma_f32_16x16x32_bf16(af, bf, acc, 0, 0, 0);
            }
            if (quad == 0) {                    // rows 0..3 valid
                #pragma unroll
                for (int r = 0; r < 4; ++r)
                    seb[r * 264 + n] = f2u(fmaxf(acc[r], 0.f));
            }
        }
    }
    // ---- stage 3b: unique L2 via MFMA + noop override -> uet[64][136] ----
    {
        int n = wv * 16 + l16;
        float bv = ub2[n];
        float ev = emb[n];
        f32x4 acc[4];
        #pragma unroll
        for (int mt = 0; mt < 4; ++mt) acc[mt] = {bv, bv, bv, bv};
        const uint16_t* brow = &uw2b[n * 128 + quad * 8];
        #pragma unroll
        for (int kk = 0; kk < 4; ++kk) {
            bf16x8 bf = *reinterpret_cast<const bf16x8*>(brow + kk * 32);
            #pragma unroll
            for (int mt = 0; mt < 4; ++mt) {
                bf16x8 af = *reinterpret_cast<const bf16x8*>(
                    &h1u[(mt * 16 + l16) * 136 + quad * 8 + kk * 32]);
                acc[mt] = __builtin_amdgcn_mfma_f32_16x16x32_bf16(af, bf, acc[mt], 0, 0, 0);
            }
        }
        #pragma unroll
        for (int mt = 0; mt < 4; ++mt)
            #pragma unroll
            for (int r = 0; r < 4; ++r) {
                int row = mt * 16 + quad * 4 + r;
                float v = (noopf[row] != 0.0f) ? ev : fmaxf(acc[mt][r], 0.f);
                uet[row * 136 + n] = f2u(v);
            }
    }
    __syncthreads();

    // ---- stages 4/5 fused: trunk L1 in 4 N-chunks of 128, double-buffered
    //      h1t; each chunk immediately accumulated into trunk-L2 regs ----
    f32x4 acc2[4][2];                           // trunk L2: M=64 x N=32 / wave
    #pragma unroll
    for (int nt = 0; nt < 2; ++nt) {
        float bv = tb2[wv * 32 + nt * 16 + l16];
        #pragma unroll
        for (int mt = 0; mt < 4; ++mt) acc2[mt][nt] = {bv, bv, bv, bv};
    }

    #pragma unroll
    for (int nc = 0; nc < 4; ++nc) {
        uint16_t* hw = (nc & 1) ? h1tb : h1ta;
        // ---- L1 chunk: M=64 x N=128, K=384; wave = M=64 x N=16 ----
        {
            f32x4 acc1[4];
            {
                float bv = tb1[nc * 128 + wv * 16 + l16];
                #pragma unroll
                for (int mt = 0; mt < 4; ++mt) acc1[mt] = {bv, bv, bv, bv};
            }
            const uint16_t* bb = tw1b + (nc * 128 + wv * 16 + l16) * 384 + quad * 8;
            bf16x8 bA = *reinterpret_cast<const bf16x8*>(bb);
            bf16x8 bB = *reinterpret_cast<const bf16x8*>(bb + 32);
            #pragma unroll
            for (int kk = 0; kk < 12; ++kk) {
                bf16x8 bN;
                if (kk < 10)
                    bN = *reinterpret_cast<const bf16x8*>(bb + (kk + 2) * 32);
                bf16x8 af[4];
                if (kk < 8) {                   // A = seb broadcast (e = mt)
                    #pragma unroll
                    for (int mt = 0; mt < 4; ++mt)
                        af[mt] = *reinterpret_cast<const bf16x8*>(
                            &seb[mt * 264 + kk * 32 + quad * 8]);
                } else {                        // A = uet rows
                    #pragma unroll
                    for (int mt = 0; mt < 4; ++mt)
                        af[mt] = *reinterpret_cast<const bf16x8*>(
                            &uet[(mt * 16 + l16) * 136 + (kk - 8) * 32 + quad * 8]);
                }
                #pragma unroll
                for (int mt = 0; mt < 4; ++mt)
                    acc1[mt] = __builtin_amdgcn_mfma_f32_16x16x32_bf16(
                        af[mt], bA, acc1[mt], 0, 0, 0);
                bA = bB; bB = bN;
            }
            #pragma unroll
            for (int mt = 0; mt < 4; ++mt)
                #pragma unroll
                for (int r = 0; r < 4; ++r) {
                    int row = mt * 16 + quad * 4 + r;
                    hw[row * 136 + wv * 16 + l16] = f2u(fmaxf(acc1[mt][r], 0.f));
                }
        }
        __syncthreads();                        // hw ready (1 barrier/chunk)
        // ---- L2 accumulate: K-chunk of 128; wave = M=64 x N=32 ----
        {
            const uint16_t* cb = tw2b + (wv * 32 + l16) * 512 + nc * 128 + quad * 8;
            bf16x8 cA[2], cB[2];
            #pragma unroll
            for (int nt = 0; nt < 2; ++nt) {
                cA[nt] = *reinterpret_cast<const bf16x8*>(cb + nt * 8192);
                cB[nt] = *reinterpret_cast<const bf16x8*>(cb + nt * 8192 + 32);
            }
            #pragma unroll
            for (int k2 = 0; k2 < 4; ++k2) {
                bf16x8 cN[2];
                if (k2 < 2) {
                    #pragma unroll
                    for (int nt = 0; nt < 2; ++nt)
                        cN[nt] = *reinterpret_cast<const bf16x8*>(
                            cb + nt * 8192 + (k2 + 2) * 32);
                }
                bf16x8 af[4];
                #pragma unroll
                for (int mt = 0; mt < 4; ++mt)
                    af[mt] = *reinterpret_cast<const bf16x8*>(
                        &hw[(mt * 16 + l16) * 136 + k2 * 32 + quad * 8]);
                #pragma unroll
                for (int mt = 0; mt < 4; ++mt)
                    #pragma unroll
                    for (int nt = 0; nt < 2; ++nt)
                        acc2[mt][nt] = __builtin_amdgcn_mfma_f32_16x16x32_bf16(
                            af[mt], cA[nt], acc2[mt][nt], 0, 0, 0);
                #pragma unroll
                for (int nt = 0; nt < 2; ++nt) { cA[nt] = cB[nt]; cB[nt] = cN[nt]; }
            }
        }
    }
    // ---- t2 epilogue (overlays h1u+uet; all uet reads completed before
    //      the nc=3 barrier, so writing here is safe) ----
    #pragma unroll
    for (int mt = 0; mt < 4; ++mt)
        #pragma unroll
        for (int nt = 0; nt < 2; ++nt)
            #pragma unroll
            for (int r = 0; r < 4; ++r) {
                int row = mt * 16 + quad * 4 + r;
                int col = wv * 32 + nt * 16 + l16;
                t2[row * 264 + col] = f2u(fmaxf(acc2[mt][nt][r], 0.f));
            }
    __syncthreads();

    // ---- heads: wave wv does rows 8wv..8wv+7 ----
    {
        float vwf[4], dwf[4];
        #pragma unroll
        for (int j = 0; j < 4; ++j) {
            vwf[j] = vw[lane + 64 * j];
            dwf[j] = dw[lane + 64 * j];
        }
        const float vbf = vb[0], dbf = db[0];
        #pragma unroll
        for (int rr = 0; rr < 8; ++rr) {
            int row = wv * 8 + rr;
            float sv = 0.f, sd = 0.f;
            #pragma unroll
            for (int j = 0; j < 4; ++j) {
                float tv = u2f(t2[row * 264 + lane + 64 * j]);
                sv += tv * vwf[j];
                sd += tv * dwf[j];
            }
            #pragma unroll
            for (int off = 32; off > 0; off >>= 1) {
                sv += __shfl_down(sv, off);
                sd += __shfl_down(sd, off);
            }
            if (lane == 0) {
                int g = blockIdx.x * 64 + row;
                out[g] = sv + vbf;
                float z = sd + dbf;
                float sig = 1.f / (1.f + __expf(-z));
                out[B_ * 16 + g] = sig * 0.4f + 0.1f;
            }
        }
    }
}

extern "C" void kernel_launch(void* const* d_in, const int* in_sizes, int n_in,
                              void* d_out, int out_size, void* d_ws, size_t ws_size,
                              hipStream_t stream) {
    const float* obs = (const float*)d_in[0];
    const float* sw1 = (const float*)d_in[1];
    const float* sb1 = (const float*)d_in[2];
    const float* sw2 = (const float*)d_in[3];
    const float* sb2 = (const float*)d_in[4];
    const float* uw1 = (const float*)d_in[5];
    const float* ub1 = (const float*)d_in[6];
    const float* uw2 = (const float*)d_in[7];
    const float* ub2 = (const float*)d_in[8];
    const float* emb = (const float*)d_in[9];
    const float* tw1 = (const float*)d_in[10];
    const float* tb1 = (const float*)d_in[11];
    const float* tw2 = (const float*)d_in[12];
    const float* tb2 = (const float*)d_in[13];
    const float* vw  = (const float*)d_in[14];
    const float* vb  = (const float*)d_in[15];
    const float* dw  = (const float*)d_in[16];
    const float* db  = (const float*)d_in[17];

    uint16_t* wsb = (uint16_t*)d_ws;

    k_conv<<<WTOT / 1024, 256, 0, stream>>>(tw1, tw2, uw2, sw2, wsb);
    k_main<<<B_ / 4, 512, 0, stream>>>(obs, sw1, sb1, sb2, uw1, ub1, ub2, emb,
                                       tb1, tb2, vw, vb, dw, db, wsb,
                                       (float*)d_out);
}

// Round 7
// 285.121 us; speedup vs baseline: 10.7848x; 1.0341x over previous
//
#include <hip/hip_runtime.h>
#include <stdint.h>

// GaitnetActor B=8192, OPT=16. Round 7: raise MFMA:LDS-read ratio to 2:1.
// M=64 rows/block (4 batch elems), grid 2048, 8 waves. Trunk L1 wave tile
// M=64xN=32 (2 chunks of 256 neurons), L2 K-chunk 256. Stage-3 wave split
// (waves 0-3 unique-L2, waves 4-7 shared-L2). LDS 73.75 KB -> 2 blocks/CU.
// bf16 MFMA / fp32 accum. out[0:131072]=logits fp32, [131072:262144]=duration.

static constexpr int B_ = 8192;

typedef __attribute__((ext_vector_type(8))) short bf16x8;
typedef __attribute__((ext_vector_type(4))) float f32x4;

__device__ __forceinline__ float u2f(uint16_t u) {
    union { uint32_t i; float f; } c; c.i = (uint32_t)u << 16; return c.f;
}
__device__ __forceinline__ uint16_t f2u(float f) {
    union { float f; uint32_t i; } c; c.f = f;
    uint32_t x = c.i;
    return (uint16_t)((x + 0x7FFFu + ((x >> 16) & 1u)) >> 16);
}

// ws elem offsets (uint16): tw1 512x384, tw2 256x512, uw2 128x128, sw2 256x256
static constexpr int WTW1 = 0;
static constexpr int WTW2 = 196608;
static constexpr int WUW2 = 327680;
static constexpr int WSW2 = 344064;
static constexpr int WTOT = 409600;

__global__ __launch_bounds__(256) void k_conv(
    const float* __restrict__ tw1, const float* __restrict__ tw2,
    const float* __restrict__ uw2, const float* __restrict__ sw2,
    uint16_t* __restrict__ ws)
{
    int i = (blockIdx.x * 256 + threadIdx.x) * 4;
    const float* src;
    if (i < WTW2)      src = tw1 + i;
    else if (i < WUW2) src = tw2 + (i - WTW2);
    else if (i < WSW2) src = uw2 + (i - WUW2);
    else               src = sw2 + (i - WSW2);
    float4 v = *reinterpret_cast<const float4*>(src);
    ushort4 o;
    o.x = f2u(v.x); o.y = f2u(v.y); o.z = f2u(v.z); o.w = f2u(v.w);
    *reinterpret_cast<ushort4*>(ws + i) = o;
}

// LDS layout (bytes). Elem strides 136/264 -> dword stride %32 == 4.
static constexpr int OBS_OFF  = 0;       // float [4][152] = 2432 (uniq @ +24)
static constexpr int NOOP_OFF = 2432;    // float [64]     = 256
static constexpr int SEB_OFF  = 2688;    // bf16  [4][264] = 2112
static constexpr int H1S_OFF  = 4800;    // bf16  [4][264] = 2112
static constexpr int H1U_OFF  = 6912;    // bf16  [64][136]= 17408
static constexpr int UET_OFF  = 24320;   // bf16  [64][136]= 17408
static constexpr int H1T_OFF  = 41728;   // bf16  [64][264]= 33792 (256-chunk)
static constexpr int T2_OFF   = H1U_OFF; // bf16  [64][264]= 33792 (overlay)
static constexpr int SMEM_SZ  = 75520;   // 73.75 KB -> 2 blocks/CU

__global__ __launch_bounds__(512, 4) void k_main(
    const float* __restrict__ obs,
    const float* __restrict__ sw1, const float* __restrict__ sb1,
    const float* __restrict__ sb2,
    const float* __restrict__ uw1, const float* __restrict__ ub1,
    const float* __restrict__ ub2, const float* __restrict__ emb,
    const float* __restrict__ tb1, const float* __restrict__ tb2,
    const float* __restrict__ vw,  const float* __restrict__ vb,
    const float* __restrict__ dw,  const float* __restrict__ db,
    const uint16_t* __restrict__ wsb,
    float* __restrict__ out)
{
    __shared__ __align__(16) char smem[SMEM_SZ];
    float*    obsl  = (float*)(smem + OBS_OFF);
    float*    noopf = (float*)(smem + NOOP_OFF);
    uint16_t* seb   = (uint16_t*)(smem + SEB_OFF);
    uint16_t* h1s   = (uint16_t*)(smem + H1S_OFF);
    uint16_t* h1u   = (uint16_t*)(smem + H1U_OFF);
    uint16_t* uet   = (uint16_t*)(smem + UET_OFF);
    uint16_t* h1t   = (uint16_t*)(smem + H1T_OFF);
    uint16_t* t2    = (uint16_t*)(smem + T2_OFF);

    const int t    = threadIdx.x;
    const int wv   = t >> 6;
    const int lane = t & 63;
    const int quad = lane >> 4;
    const int l16  = lane & 15;
    const int b0   = blockIdx.x * 4;

    const uint16_t* tw1b = wsb + WTW1;
    const uint16_t* tw2b = wsb + WTW2;
    const uint16_t* uw2b = wsb + WUW2;
    const uint16_t* sw2b = wsb + WSW2;

    // ---- stage 1: load 4 obs rows, uniq cols shifted +2 for alignment ----
    for (int i = t; i < 600; i += 512) {
        int e = i / 150, c = i - e * 150;
        int dst = (c < 22) ? c : c + 2;
        obsl[e * 152 + dst] = obs[(size_t)(b0 + e) * 150 + c];
    }
    __syncthreads();

    // ---- stage 2: small layer-1s (VALU, vectorized LDS reads) ----
    if (t < 64) {
        int e = t >> 4, o = t & 15;
        noopf[t] = (obsl[e * 152 + 24 + o * 8] == 1.0f) ? 1.0f : 0.0f;
    }
    {   // shared L1: 4 elems x 256 neurons
        const int n = t & 255;
        float w[22];
        #pragma unroll
        for (int k = 0; k < 22; ++k) w[k] = sw1[n * 22 + k];
        const float bias = sb1[n];
        #pragma unroll
        for (int ii = 0; ii < 2; ++ii) {
            int e = (t >> 8) + 2 * ii;
            const float2* xp = (const float2*)&obsl[e * 152];
            float a = bias;
            #pragma unroll
            for (int k = 0; k < 11; ++k) {
                float2 x2 = xp[k];
                a += w[2 * k] * x2.x + w[2 * k + 1] * x2.y;
            }
            h1s[e * 264 + n] = f2u(fmaxf(a, 0.f));
        }
    }
    {   // unique L1: 64 rows x 128 neurons
        const int n = t & 127;
        float w[8];
        #pragma unroll
        for (int k = 0; k < 8; ++k) w[k] = uw1[n * 8 + k];
        const float bias = ub1[n];
        #pragma unroll
        for (int ii = 0; ii < 16; ++ii) {
            int row = (t >> 7) + 4 * ii;
            const float4* xp = (const float4*)&obsl[(row >> 4) * 152 + 24 + (row & 15) * 8];
            float4 xa = xp[0], xb = xp[1];
            float a = bias + w[0] * xa.x + w[1] * xa.y + w[2] * xa.z + w[3] * xa.w
                           + w[4] * xb.x + w[5] * xb.y + w[6] * xb.z + w[7] * xb.w;
            h1u[row * 136 + n] = f2u(fmaxf(a, 0.f));
        }
    }
    __syncthreads();

    // ---- stage 3 (wave-specialized) ----
    if (wv < 4) {
        // unique L2: wave tile M=64 x N=32, K=128 -> uet
        f32x4 acc[4][2];
        float ev[2];
        #pragma unroll
        for (int nt = 0; nt < 2; ++nt) {
            int n = wv * 32 + nt * 16 + l16;
            float bv = ub2[n];
            ev[nt] = emb[n];
            #pragma unroll
            for (int mt = 0; mt < 4; ++mt) acc[mt][nt] = {bv, bv, bv, bv};
        }
        #pragma unroll
        for (int kk = 0; kk < 4; ++kk) {
            bf16x8 bfr[2];
            #pragma unroll
            for (int nt = 0; nt < 2; ++nt)
                bfr[nt] = *reinterpret_cast<const bf16x8*>(
                    &uw2b[(wv * 32 + nt * 16 + l16) * 128 + kk * 32 + quad * 8]);
            bf16x8 af[4];
            #pragma unroll
            for (int mt = 0; mt < 4; ++mt)
                af[mt] = *reinterpret_cast<const bf16x8*>(
                    &h1u[(mt * 16 + l16) * 136 + kk * 32 + quad * 8]);
            #pragma unroll
            for (int mt = 0; mt < 4; ++mt)
                #pragma unroll
                for (int nt = 0; nt < 2; ++nt)
                    acc[mt][nt] = __builtin_amdgcn_mfma_f32_16x16x32_bf16(
                        af[mt], bfr[nt], acc[mt][nt], 0, 0, 0);
        }
        #pragma unroll
        for (int mt = 0; mt < 4; ++mt)
            #pragma unroll
            for (int nt = 0; nt < 2; ++nt)
                #pragma unroll
                for (int r = 0; r < 4; ++r) {
                    int row = mt * 16 + quad * 4 + r;
                    float v = (noopf[row] != 0.0f) ? ev[nt] : fmaxf(acc[mt][nt][r], 0.f);
                    uet[row * 136 + wv * 32 + nt * 16 + l16] = f2u(v);
                }
    } else {
        // shared L2: wave tile M=16(4 valid) x N=64, K=256 -> seb
        const int w4 = wv - 4;
        f32x4 acc[4];
        #pragma unroll
        for (int nt = 0; nt < 4; ++nt) {
            float bv = sb2[w4 * 64 + nt * 16 + l16];
            acc[nt] = {bv, bv, bv, bv};
        }
        const uint16_t* arow = &h1s[l16 * 264 + quad * 8];  // rows>=4: finite junk
        #pragma unroll
        for (int kk = 0; kk < 8; ++kk) {
            bf16x8 af = *reinterpret_cast<const bf16x8*>(arow + kk * 32);
            #pragma unroll
            for (int nt = 0; nt < 4; ++nt) {
                bf16x8 bf = *reinterpret_cast<const bf16x8*>(
                    &sw2b[(w4 * 64 + nt * 16 + l16) * 256 + kk * 32 + quad * 8]);
                acc[nt] = __builtin_amdgcn_mfma_f32_16x16x32_bf16(af, bf, acc[nt], 0, 0, 0);
            }
        }
        if (quad == 0) {                        // rows 0..3 valid
            #pragma unroll
            for (int nt = 0; nt < 4; ++nt)
                #pragma unroll
                for (int r = 0; r < 4; ++r)
                    seb[r * 264 + w4 * 64 + nt * 16 + l16] = f2u(fmaxf(acc[nt][r], 0.f));
        }
    }
    __syncthreads();

    // ---- stages 4/5 fused: 2 N-chunks of 256 trunk-L1 neurons ----
    f32x4 acc2[4][2];                           // trunk L2: M=64 x N=32 / wave
    #pragma unroll
    for (int nt = 0; nt < 2; ++nt) {
        float bv = tb2[wv * 32 + nt * 16 + l16];
        #pragma unroll
        for (int mt = 0; mt < 4; ++mt) acc2[mt][nt] = {bv, bv, bv, bv};
    }

    #pragma unroll
    for (int nc = 0; nc < 2; ++nc) {
        // ---- L1 chunk: M=64 x N=256, K=384; wave = M=64 x N=32 ----
        {
            f32x4 acc1[4][2];
            #pragma unroll
            for (int nt = 0; nt < 2; ++nt) {
                float bv = tb1[nc * 256 + wv * 32 + nt * 16 + l16];
                #pragma unroll
                for (int mt = 0; mt < 4; ++mt) acc1[mt][nt] = {bv, bv, bv, bv};
            }
            const uint16_t* bb = tw1b + (nc * 256 + wv * 32 + l16) * 384 + quad * 8;
            bf16x8 bc[2], bn[2];
            bc[0] = *reinterpret_cast<const bf16x8*>(bb);
            bc[1] = *reinterpret_cast<const bf16x8*>(bb + 6144);
            #pragma unroll
            for (int kk = 0; kk < 12; ++kk) {
                if (kk < 11) {
                    bn[0] = *reinterpret_cast<const bf16x8*>(bb + (kk + 1) * 32);
                    bn[1] = *reinterpret_cast<const bf16x8*>(bb + 6144 + (kk + 1) * 32);
                }
                bf16x8 af[4];
                if (kk < 8) {                   // A = seb broadcast (e = mt)
                    #pragma unroll
                    for (int mt = 0; mt < 4; ++mt)
                        af[mt] = *reinterpret_cast<const bf16x8*>(
                            &seb[mt * 264 + kk * 32 + quad * 8]);
                } else {                        // A = uet rows
                    #pragma unroll
                    for (int mt = 0; mt < 4; ++mt)
                        af[mt] = *reinterpret_cast<const bf16x8*>(
                            &uet[(mt * 16 + l16) * 136 + (kk - 8) * 32 + quad * 8]);
                }
                #pragma unroll
                for (int mt = 0; mt < 4; ++mt)
                    #pragma unroll
                    for (int nt = 0; nt < 2; ++nt)
                        acc1[mt][nt] = __builtin_amdgcn_mfma_f32_16x16x32_bf16(
                            af[mt], bc[nt], acc1[mt][nt], 0, 0, 0);
                bc[0] = bn[0]; bc[1] = bn[1];
            }
            #pragma unroll
            for (int mt = 0; mt < 4; ++mt)
                #pragma unroll
                for (int nt = 0; nt < 2; ++nt)
                    #pragma unroll
                    for (int r = 0; r < 4; ++r) {
                        int row = mt * 16 + quad * 4 + r;
                        h1t[row * 264 + wv * 32 + nt * 16 + l16] =
                            f2u(fmaxf(acc1[mt][nt][r], 0.f));
                    }
        }
        __syncthreads();                        // h1t chunk ready
        // ---- L2 accumulate: K-chunk of 256; wave = M=64 x N=32 ----
        {
            const uint16_t* cb = tw2b + (wv * 32 + l16) * 512 + nc * 256 + quad * 8;
            bf16x8 cc[2], cn[2];
            cc[0] = *reinterpret_cast<const bf16x8*>(cb);
            cc[1] = *reinterpret_cast<const bf16x8*>(cb + 8192);
            #pragma unroll
            for (int k2 = 0; k2 < 8; ++k2) {
                if (k2 < 7) {
                    cn[0] = *reinterpret_cast<const bf16x8*>(cb + (k2 + 1) * 32);
                    cn[1] = *reinterpret_cast<const bf16x8*>(cb + 8192 + (k2 + 1) * 32);
                }
                bf16x8 af[4];
                #pragma unroll
                for (int mt = 0; mt < 4; ++mt)
                    af[mt] = *reinterpret_cast<const bf16x8*>(
                        &h1t[(mt * 16 + l16) * 264 + k2 * 32 + quad * 8]);
                #pragma unroll
                for (int mt = 0; mt < 4; ++mt)
                    #pragma unroll
                    for (int nt = 0; nt < 2; ++nt)
                        acc2[mt][nt] = __builtin_amdgcn_mfma_f32_16x16x32_bf16(
                            af[mt], cc[nt], acc2[mt][nt], 0, 0, 0);
                cc[0] = cn[0]; cc[1] = cn[1];
            }
        }
        if (nc == 0) __syncthreads();           // h1t consumed before overwrite
    }
    // ---- t2 epilogue (overlays h1u+uet; uet reads all done pre-barrier;
    //      other waves' L2 only touches h1t, so immediate write is safe) ----
    #pragma unroll
    for (int mt = 0; mt < 4; ++mt)
        #pragma unroll
        for (int nt = 0; nt < 2; ++nt)
            #pragma unroll
            for (int r = 0; r < 4; ++r) {
                int row = mt * 16 + quad * 4 + r;
                t2[row * 264 + wv * 32 + nt * 16 + l16] =
                    f2u(fmaxf(acc2[mt][nt][r], 0.f));
            }
    __syncthreads();

    // ---- heads: wave wv does rows 8wv..8wv+7 ----
    {
        float vwf[4], dwf[4];
        #pragma unroll
        for (int j = 0; j < 4; ++j) {
            vwf[j] = vw[lane + 64 * j];
            dwf[j] = dw[lane + 64 * j];
        }
        const float vbf = vb[0], dbf = db[0];
        #pragma unroll
        for (int rr = 0; rr < 8; ++rr) {
            int row = wv * 8 + rr;
            float sv = 0.f, sd = 0.f;
            #pragma unroll
            for (int j = 0; j < 4; ++j) {
                float tv = u2f(t2[row * 264 + lane + 64 * j]);
                sv += tv * vwf[j];
                sd += tv * dwf[j];
            }
            #pragma unroll
            for (int off = 32; off > 0; off >>= 1) {
                sv += __shfl_down(sv, off);
                sd += __shfl_down(sd, off);
            }
            if (lane == 0) {
                int g = blockIdx.x * 64 + row;
                out[g] = sv + vbf;
                float z = sd + dbf;
                float sig = 1.f / (1.f + __expf(-z));
                out[B_ * 16 + g] = sig * 0.4f + 0.1f;
            }
        }
    }
}

extern "C" void kernel_launch(void* const* d_in, const int* in_sizes, int n_in,
                              void* d_out, int out_size, void* d_ws, size_t ws_size,
                              hipStream_t stream) {
    const float* obs = (const float*)d_in[0];
    const float* sw1 = (const float*)d_in[1];
    const float* sb1 = (const float*)d_in[2];
    const float* sw2 = (const float*)d_in[3];
    const float* sb2 = (const float*)d_in[4];
    const float* uw1 = (const float*)d_in[5];
    const float* ub1 = (const float*)d_in[6];
    const float* uw2 = (const float*)d_in[7];
    const float* ub2 = (const float*)d_in[8];
    const float* emb = (const float*)d_in[9];
    const float* tw1 = (const float*)d_in[10];
    const float* tb1 = (const float*)d_in[11];
    const float* tw2 = (const float*)d_in[12];
    const float* tb2 = (const float*)d_in[13];
    const float* vw  = (const float*)d_in[14];
    const float* vb  = (const float*)d_in[15];
    const float* dw  = (const float*)d_in[16];
    const float* db  = (const float*)d_in[17];

    uint16_t* wsb = (uint16_t*)d_ws;

    k_conv<<<WTOT / 1024, 256, 0, stream>>>(tw1, tw2, uw2, sw2, wsb);
    k_main<<<B_ / 4, 512, 0, stream>>>(obs, sw1, sb1, sb2, uw1, ub1, ub2, emb,
                                       tb1, tb2, vw, vb, dw, db, wsb,
                                       (float*)d_out);
}